// Round 2
// baseline (509.629 us; speedup 1.0000x reference)
//
#include <hip/hip_runtime.h>

// Fused LayerNorm-LSTM cell + zoneout for MI355X (gfx950).
// GEMM: concat(x,h)[65536x512] @ W[512x1024] via mfma_f32_16x16x32_f16,
// fused with block-LN(4x256), gates, LN(new_c), zoneout.
// Kernel 0 pre-transposes W to Wt[1024][512] fp16 in d_ws (needs 1 MB ws).
//
// R3: W bypasses LDS entirely. R2 post-mortem: conflicts (exactly 2^23) were
// ALL epilogue preT reads (stride-20 4-way), and every __syncthreads emitted
// vmcnt(0) draining the in-flight W global_load_lds + A loads -> lockstep
// stall at 32 barriers/block with only 2 waves/SIMD. Now:
//  - B-fragments load straight from L2 to registers (Wt is 1MB, L2-resident;
//    same global access pattern as before). Compiler emits COUNTED vmcnt
//    before each MFMA use; loads stay in flight across barriers (T4).
//  - Only the 4KB A-tile is shared: double-buffered, ONE raw s_barrier per
//    iter preceded by lgkmcnt(0) only (never vmcnt). A issued 2 iters ahead.
//  - LDS traffic/iter: 164KB -> 36KB.
//  - Epilogue: preT row-slot XOR (row ^= 2*bit4(n), pair-swapped store) kills
//    the 4-way conflicts; bias folded into preT store; g1/b1/g2/b2 staged in
//    LDS; raw barriers so pass p+1 doesn't drain pass p's output stores.

#define NTHREADS 512
#define TILE_M 64
#define PRE_STRIDE 20  // halfs per n-row in epilogue scratch (16 rows + 4 pad)

typedef _Float16 half8 __attribute__((ext_vector_type(8)));
typedef _Float16 half4v __attribute__((ext_vector_type(4)));
typedef float float4v __attribute__((ext_vector_type(4)));

__device__ __forceinline__ float sigm(float x) {
  return __fdividef(1.0f, 1.0f + __expf(-x));
}
__device__ __forceinline__ float tanh_fast(float x) {
  return 2.0f * __fdividef(1.0f, 1.0f + __expf(-2.0f * x)) - 1.0f;
}
// Barrier WITHOUT the implicit vmcnt(0) drain __syncthreads carries.
// Only LDS ops need cross-wave visibility here; register global loads may
// stay in flight across it (counted vmcnt at their use sites).
__device__ __forceinline__ void bar_lgkm() {
  asm volatile("s_waitcnt lgkmcnt(0)\ns_barrier" ::: "memory");
}

// ---- Kernel 0: W[512][1024] fp32 -> Wt[1024][512] fp16 (tiled transpose) ----
__global__ __launch_bounds__(256) void wt_kernel(const float* __restrict__ W,
                                                 _Float16* __restrict__ Wt) {
  __shared__ float tile[64][65];
  const int bn = blockIdx.x << 6;  // n block (16)
  const int bk = blockIdx.y << 6;  // k block (8)
  const int tid = threadIdx.x;
#pragma unroll
  for (int i = 0; i < 16; ++i) {
    int idx = (i << 8) + tid;
    int kk = idx >> 6, nn = idx & 63;
    tile[kk][nn] = W[(size_t)(bk + kk) * 1024 + bn + nn];
  }
  __syncthreads();
#pragma unroll
  for (int i = 0; i < 16; ++i) {
    int idx = (i << 8) + tid;
    int nn = idx >> 6, kk = idx & 63;
    Wt[(size_t)(bn + nn) * 512 + bk + kk] = (_Float16)tile[kk][nn];
  }
}

// ---- Main fused kernel ----
// Block: 64 rows x all 1024 cols, 8 waves (wave w owns cols w*64..+63 of each
// 512-half). K-loop BK=32. LDS: abuf 2x4KB (K-loop) | epilogue overlay:
// preT[1024][PRE_STRIDE] 40KB + g1l/b1l/g2l/b2l 10.25KB -> 51200 B dynamic.
__global__ __launch_bounds__(NTHREADS, 2) void lstm_fused(
    const float* __restrict__ x, const float* __restrict__ hin,
    const float* __restrict__ cin, const _Float16* __restrict__ Wt,
    const float* __restrict__ bias, const float* __restrict__ g1,
    const float* __restrict__ b1, const float* __restrict__ g2,
    const float* __restrict__ b2, const float* __restrict__ mhp,
    const float* __restrict__ mcp, float* __restrict__ out) {
  extern __shared__ char smem[];
  _Float16* abuf = (_Float16*)smem;  // 2 x 4KB A double-buffer (K-loop)
  _Float16* preT = (_Float16*)smem;  // 40KB epilogue overlay (reuses abuf)
  float* g1l = (float*)(smem + 40960);
  float* b1l = (float*)(smem + 45056);
  float* g2l = (float*)(smem + 49152);
  float* b2l = (float*)(smem + 50176);

  const int tid = threadIdx.x;
  const int wave = tid >> 6;
  const int lane = tid & 63;
  const int l15 = lane & 15;
  const int quad = lane >> 4;
  const int blockRow = blockIdx.x * TILE_M;

  // Stage LN gains/biases to LDS once (region disjoint from abuf).
  g1l[tid] = g1[tid];
  g1l[tid + 512] = g1[tid + 512];
  b1l[tid] = b1[tid];
  b1l[tid + 512] = b1[tid + 512];
  if (tid < 256) {
    g2l[tid] = g2[tid];
    b2l[tid] = b2[tid];
  }

  float4v acc[4][8];
#pragma unroll
  for (int s = 0; s < 4; ++s)
#pragma unroll
    for (int c = 0; c < 8; ++c) acc[s][c] = (float4v){0.f, 0.f, 0.f, 0.f};

  // A staging: thread -> (row=tid>>3, 4 k's at (tid&7)*4), fp32->fp16,
  // 16B-chunk XOR swizzle (verified conflict-free for the b128 frag reads).
  const int arow = tid >> 3;
  const int ap4 = (tid & 7) << 2;
  const float* xrow = x + (size_t)(blockRow + arow) * 256 + ap4;
  const float* hrow = hin + (size_t)(blockRow + arow) * 256 + ap4;
  _Float16* adst =
      abuf + arow * 32 + (((ap4 >> 3) ^ ((arow ^ (arow >> 2)) & 3)) << 3) + (ap4 & 4);
  const int aslot = quad ^ ((l15 ^ (l15 >> 2)) & 3);

  // B direct-from-L2: lane (l15,quad) of wave w reads Wt row w*64+cc*16+l15,
  // k-bytes quad*16 within the 64B iter window. halfs offsets:
  // cc*8192 (16 rows.. wait: 16 rows x 512 halfs), half1 +262144, iter +32.
  const _Float16* wbase = Wt + ((size_t)(wave * 64 + l15) << 9) + (quad << 3);

  // ---- prologue: A(0) -> buf0, load B0(0), issue A(1) ----
  {
    float4 v = *(const float4*)xrow;
    *(half4v*)adst = (half4v){(_Float16)v.x, (_Float16)v.y, (_Float16)v.z, (_Float16)v.w};
  }
  half8 B0[4];
#pragma unroll
  for (int cc = 0; cc < 4; ++cc) B0[cc] = *(const half8*)(wbase + cc * 8192);
  float4 av1 = *(const float4*)(xrow + 32);  // A(1)
  bar_lgkm();

#pragma unroll 2
  for (int i = 0; i < 15; ++i) {
    // issue A(i+2) (2-iter distance covers L3/HBM latency)
    float4 av2;
    if (i < 14) {
      const float* s2p = (i + 2 < 8) ? (xrow + (i + 2) * 32) : (hrow + (i - 6) * 32);
      av2 = *(const float4*)s2p;
    }
    // issue B half1(i)
    half8 B1[4];
#pragma unroll
    for (int cc = 0; cc < 4; ++cc)
      B1[cc] = *(const half8*)(wbase + cc * 8192 + 262144 + i * 32);
    // A fragments for this iter
    const _Float16* abr = abuf + ((i & 1) << 11);
    half8 af[4];
#pragma unroll
    for (int s = 0; s < 4; ++s)
      af[s] = *(const half8*)(abr + (s * 16 + l15) * 32 + aslot * 8);
    // MFMA half0 (B0 loaded last iter; counted vmcnt at use)
    __builtin_amdgcn_s_setprio(1);
#pragma unroll
    for (int s = 0; s < 4; ++s)
#pragma unroll
      for (int cc = 0; cc < 4; ++cc)
        acc[s][cc] = __builtin_amdgcn_mfma_f32_16x16x32_f16(af[s], B0[cc], acc[s][cc], 0, 0, 0);
    __builtin_amdgcn_s_setprio(0);
    // issue B half0(i+1)
    half8 B0n[4];
#pragma unroll
    for (int cc = 0; cc < 4; ++cc)
      B0n[cc] = *(const half8*)(wbase + cc * 8192 + (i + 1) * 32);
    // MFMA half1
    __builtin_amdgcn_s_setprio(1);
#pragma unroll
    for (int s = 0; s < 4; ++s)
#pragma unroll
      for (int cc = 0; cc < 4; ++cc)
        acc[s][4 + cc] =
            __builtin_amdgcn_mfma_f32_16x16x32_f16(af[s], B1[cc], acc[s][4 + cc], 0, 0, 0);
    __builtin_amdgcn_s_setprio(0);
    // write A(i+1) into the buffer read at iter i-1 (safe: barrier(i-1)..(i))
    {
      half4v hv = {(_Float16)av1.x, (_Float16)av1.y, (_Float16)av1.z, (_Float16)av1.w};
      *(half4v*)(adst + (((i + 1) & 1) << 11)) = hv;
    }
    if (i < 14) av1 = av2;
#pragma unroll
    for (int cc = 0; cc < 4; ++cc) B0[cc] = B0n[cc];
    bar_lgkm();  // lgkm-only: A writes visible; B/global loads stay in flight
  }
  {  // ---- peeled iter 15 (no prefetch, no barrier) ----
    half8 B1[4];
#pragma unroll
    for (int cc = 0; cc < 4; ++cc)
      B1[cc] = *(const half8*)(wbase + cc * 8192 + 262144 + 15 * 32);
    const _Float16* abr = abuf + ((15 & 1) << 11);
    half8 af[4];
#pragma unroll
    for (int s = 0; s < 4; ++s)
      af[s] = *(const half8*)(abr + (s * 16 + l15) * 32 + aslot * 8);
    __builtin_amdgcn_s_setprio(1);
#pragma unroll
    for (int s = 0; s < 4; ++s)
#pragma unroll
      for (int cc = 0; cc < 4; ++cc)
        acc[s][cc] = __builtin_amdgcn_mfma_f32_16x16x32_f16(af[s], B0[cc], acc[s][cc], 0, 0, 0);
#pragma unroll
    for (int s = 0; s < 4; ++s)
#pragma unroll
      for (int cc = 0; cc < 4; ++cc)
        acc[s][4 + cc] =
            __builtin_amdgcn_mfma_f32_16x16x32_f16(af[s], B1[cc], acc[s][4 + cc], 0, 0, 0);
    __builtin_amdgcn_s_setprio(0);
  }

  // ---- Epilogue: 4 passes of 16 rows (pass p == row-stripe p) ----
  // preT store: bias folded in; row-slot flip (slot = row ^ 2*bit4(n)) via
  // pair-swapped vector -> LN reads spread 32 banks (was 4-way conflicted).
  float* out_h = out;
  float* out_c = out + (size_t)65536 * 256;
  const int er = tid >> 5;  // row in pass 0..15
  const int et = tid & 31;  // col phase: cols {et, et+32, ..., et+224}
  const int ro = er ^ (((et >> 4) & 1) << 1);  // read slot (bit4(n) == bit4(et))

#pragma unroll
  for (int p = 0; p < 4; ++p) {
    bar_lgkm();
    // write acc stripe p -> preT (col-major [n][slot]), b64 per 4 rows
#pragma unroll
    for (int c = 0; c < 8; ++c) {
      int n = ((c >> 2) << 9) + wave * 64 + ((c & 3) << 4) + l15;  // D col = lane&15
      float bn = bias[n];
      float4v a = acc[p][c];
      _Float16 e0 = (_Float16)(a.x + bn), e1 = (_Float16)(a.y + bn);
      _Float16 e2 = (_Float16)(a.z + bn), e3 = (_Float16)(a.w + bn);
      // bit4(n) == c&1: flip swaps row pairs {0,1}<->{2,3} within the quad
      half4v hv = (c & 1) ? (half4v){e2, e3, e0, e1} : (half4v){e0, e1, e2, e3};
      *(half4v*)(preT + n * PRE_STRIDE + (quad << 2)) = hv;  // rows quad*4+reg
    }
    bar_lgkm();

    const int rg = blockRow + (p << 4) + er;
    // LN1 stats per 256-chunk (bias already folded into preT)
    float mean1[4], rstd1[4];
#pragma unroll
    for (int ch = 0; ch < 4; ++ch) {
      float s = 0.f, q = 0.f;
#pragma unroll
      for (int ss = 0; ss < 8; ++ss) {
        int n = (ch << 8) + (ss << 5) + et;
        float v = (float)preT[n * PRE_STRIDE + ro];
        s += v;
        q += v * v;
      }
#pragma unroll
      for (int m = 1; m < 32; m <<= 1) {
        s += __shfl_xor(s, m, 32);
        q += __shfl_xor(q, m, 32);
      }
      float mu = s * (1.0f / 256.0f);
      mean1[ch] = mu;
      rstd1[ch] = __frsqrt_rn(q * (1.0f / 256.0f) - mu * mu + 1e-5f);
    }

    float ncp[8], so[8], cv[8];
    float s2 = 0.f, q2 = 0.f;
#pragma unroll
    for (int ss = 0; ss < 8; ++ss) {
      int hc = (ss << 5) + et;
      float iv = ((float)preT[(hc)*PRE_STRIDE + ro] - mean1[0]) * rstd1[0] * g1l[hc] + b1l[hc];
      float jv = ((float)preT[(256 + hc) * PRE_STRIDE + ro] - mean1[1]) * rstd1[1] * g1l[256 + hc] + b1l[256 + hc];
      float fv = ((float)preT[(512 + hc) * PRE_STRIDE + ro] - mean1[2]) * rstd1[2] * g1l[512 + hc] + b1l[512 + hc];
      float ov = ((float)preT[(768 + hc) * PRE_STRIDE + ro] - mean1[3]) * rstd1[3] * g1l[768 + hc] + b1l[768 + hc];
      float cval = cin[(size_t)rg * 256 + hc];
      float nc = cval * sigm(fv + 1.0f) + sigm(iv) * tanh_fast(jv);
      ncp[ss] = nc;
      so[ss] = sigm(ov);
      cv[ss] = cval;
      s2 += nc;
      q2 += nc * nc;
    }
#pragma unroll
    for (int m = 1; m < 32; m <<= 1) {
      s2 += __shfl_xor(s2, m, 32);
      q2 += __shfl_xor(q2, m, 32);
    }
    float mu2 = s2 * (1.0f / 256.0f);
    float rstd2 = __frsqrt_rn(q2 * (1.0f / 256.0f) - mu2 * mu2 + 1e-5f);
#pragma unroll
    for (int ss = 0; ss < 8; ++ss) {
      int hc = (ss << 5) + et;
      size_t gi = (size_t)rg * 256 + hc;
      float ncn = (ncp[ss] - mu2) * rstd2 * g2l[hc] + b2l[hc];
      float nh = tanh_fast(ncn) * so[ss];
      float hval = hin[gi];
      out_h[gi] = (mhp[gi] < 0.7f) ? nh : hval;  // zoneout: mask<keep -> new
      out_c[gi] = (mcp[gi] < 0.7f) ? ncn : cv[ss];
    }
  }
}

extern "C" void kernel_launch(void* const* d_in, const int* in_sizes, int n_in,
                              void* d_out, int out_size, void* d_ws, size_t ws_size,
                              hipStream_t stream) {
  (void)in_sizes; (void)n_in; (void)out_size; (void)ws_size;
  const float* x = (const float*)d_in[0];
  const float* h = (const float*)d_in[1];
  const float* c = (const float*)d_in[2];
  const float* W = (const float*)d_in[3];
  const float* bias = (const float*)d_in[4];
  const float* g1 = (const float*)d_in[5];
  const float* b1 = (const float*)d_in[6];
  const float* g2 = (const float*)d_in[7];
  const float* b2 = (const float*)d_in[8];
  const float* mh = (const float*)d_in[9];
  const float* mc = (const float*)d_in[10];
  _Float16* Wt = (_Float16*)d_ws;  // 1 MB

  wt_kernel<<<dim3(16, 8), dim3(256), 0, stream>>>(W, Wt);
  lstm_fused<<<dim3(1024), dim3(NTHREADS), 51200, stream>>>(
      x, h, c, Wt, bias, g1, b1, g2, b2, mh, mc, (float*)d_out);
}

// Round 3
// 485.135 us; speedup vs baseline: 1.0505x; 1.0505x over previous
//
#include <hip/hip_runtime.h>

// Fused LayerNorm-LSTM cell + zoneout for MI355X (gfx950).
// GEMM: concat(x,h)[65536x512] @ W[512x1024] via mfma_f32_16x16x32_f16,
// fused with block-LN(4x256), gates, LN(new_c), zoneout.
// Kernel 0 pre-transposes W to Wt[1024][512] fp16 in d_ws (needs 1 MB ws).
//
// R4: back to R2's LDS W staging (R3's direct-to-reg B regressed: per-use L2
// latency exposed + forced register-copy drains; regs pinned at the 256 cliff
// so deeper reg prefetch impossible). Fix R2's real problem instead: its four
// vmcnt(0)-draining __syncthreads per iter. Now two raw barriers per iter
// with COUNTED waits (T3/T4):
//   h0: issue Wh1(i) (4x global_load_lds), load av=A(i+1), MFMA half0,
//       then "vmcnt(1) lgkmcnt(0); s_barrier"  -> Wh1(i) landed, av flying.
//   h1: issue Wh0(i+1), MFMA half1, ds_write av (compiler-counted wait),
//       then "vmcnt(0) lgkmcnt(0); s_barrier"  -> Wh0(i+1) + A visible.
// Every W batch is issued one full phase (~250-400cy) before its consuming
// barrier (> L2 ~225cy); A loads never get force-drained by a W wait.
// Buffers rewritten in place (reader phase ends at the barrier preceding the
// rewrite issue) - no rotation. Epilogue = R3's (bias-folded preT, pair-swap
// swizzle, LDS LN params now staged inside pass 0 since K-loop owns 68KB).

#define NTHREADS 512
#define TILE_M 64
#define PRE_STRIDE 20  // halfs per n-row in epilogue scratch (16 rows + 4 pad)

#define BARRIER_VM(N) \
  asm volatile("s_waitcnt vmcnt(" #N ") lgkmcnt(0)\ns_barrier" ::: "memory")

typedef _Float16 half8 __attribute__((ext_vector_type(8)));
typedef _Float16 half4v __attribute__((ext_vector_type(4)));
typedef float float4v __attribute__((ext_vector_type(4)));

__device__ __forceinline__ void async16(const void* g, void* l) {
  __builtin_amdgcn_global_load_lds(
      (const __attribute__((address_space(1))) unsigned int*)g,
      (__attribute__((address_space(3))) unsigned int*)l, 16, 0, 0);
}

__device__ __forceinline__ float sigm(float x) {
  return __fdividef(1.0f, 1.0f + __expf(-x));
}
__device__ __forceinline__ float tanh_fast(float x) {
  return 2.0f * __fdividef(1.0f, 1.0f + __expf(-2.0f * x)) - 1.0f;
}
// lgkm-only barrier for the epilogue (out-stores of pass p-1 stay in flight).
__device__ __forceinline__ void bar_lgkm() {
  asm volatile("s_waitcnt lgkmcnt(0)\ns_barrier" ::: "memory");
}

// ---- Kernel 0: W[512][1024] fp32 -> Wt[1024][512] fp16 (tiled transpose) ----
__global__ __launch_bounds__(256) void wt_kernel(const float* __restrict__ W,
                                                 _Float16* __restrict__ Wt) {
  __shared__ float tile[64][65];
  const int bn = blockIdx.x << 6;  // n block (16)
  const int bk = blockIdx.y << 6;  // k block (8)
  const int tid = threadIdx.x;
#pragma unroll
  for (int i = 0; i < 16; ++i) {
    int idx = (i << 8) + tid;
    int kk = idx >> 6, nn = idx & 63;
    tile[kk][nn] = W[(size_t)(bk + kk) * 1024 + bn + nn];
  }
  __syncthreads();
#pragma unroll
  for (int i = 0; i < 16; ++i) {
    int idx = (i << 8) + tid;
    int nn = idx >> 6, kk = idx & 63;
    Wt[(size_t)(bn + nn) * 512 + bk + kk] = (_Float16)tile[kk][nn];
  }
}

// ---- Main fused kernel ----
// Block: 64 rows x all 1024 cols, 8 waves (wave w owns cols w*64 of each
// 512-half). K-loop BK=32 in two half-phases.
// LDS phase A: abuf 4KB | wTh0 32KB | wTh1 32KB  (69632 B).
// Phase B epilogue overlays preT[1024][PRE_STRIDE] (40KB) + LN params 10.25KB.
__global__ __launch_bounds__(NTHREADS, 2) void lstm_fused(
    const float* __restrict__ x, const float* __restrict__ hin,
    const float* __restrict__ cin, const _Float16* __restrict__ Wt,
    const float* __restrict__ bias, const float* __restrict__ g1,
    const float* __restrict__ b1, const float* __restrict__ g2,
    const float* __restrict__ b2, const float* __restrict__ mhp,
    const float* __restrict__ mcp, float* __restrict__ out) {
  extern __shared__ char smem[];
  _Float16* abuf = (_Float16*)smem;             // 4KB  A tile
  _Float16* wTh0 = (_Float16*)(smem + 4096);    // 32KB W cols 0..511
  _Float16* wTh1 = (_Float16*)(smem + 36864);   // 32KB W cols 512..1023
  _Float16* preT = (_Float16*)smem;             // 40KB (phase B overlay)
  float* g1l = (float*)(smem + 40960);          // phase B only
  float* b1l = (float*)(smem + 45056);
  float* g2l = (float*)(smem + 49152);
  float* b2l = (float*)(smem + 50176);

  const int tid = threadIdx.x;
  const int wave = tid >> 6;
  const int lane = tid & 63;
  const int l15 = lane & 15;
  const int quad = lane >> 4;
  const int blockRow = blockIdx.x * TILE_M;

  float4v acc[4][8];
#pragma unroll
  for (int s = 0; s < 4; ++s)
#pragma unroll
    for (int c = 0; c < 8; ++c) acc[s][c] = (float4v){0.f, 0.f, 0.f, 0.f};

  // A staging: thread -> (row=tid>>3, 4 k's at (tid&7)*4), fp32->fp16,
  // 16B-chunk XOR swizzle (R2-proven conflict-free for the b128 frag reads).
  const int arow = tid >> 3;
  const int ap4 = (tid & 7) << 2;
  const float* xrow = x + (size_t)(blockRow + arow) * 256 + ap4;
  const float* hrow = hin + (size_t)(blockRow + arow) * 256 + ap4;
  _Float16* adst =
      abuf + arow * 32 + (((ap4 >> 3) ^ ((arow ^ (arow >> 2)) & 3)) << 3) + (ap4 & 4);
  const int aslot = quad ^ ((l15 ^ (l15 >> 2)) & 3);

  // W staging: lane-linear LDS dest (global_load_lds constraint); global chunk
  // XOR-permuted with the matching row swizzle (R2-proven).
  const int wnl0 = tid >> 2;                  // local n row 0..127 (+ it*128)
  const int wj = (tid & 3) ^ ((wnl0 ^ (wnl0 >> 2)) & 3);
  const char* wg = (const char*)Wt + (size_t)wnl0 * 1024 + wj * 16;
  char* wl0 = (char*)wTh0 + tid * 16;
  char* wl1 = (char*)wTh1 + tid * 16;

  // ---- prologue: stage A(0); issue Wh0(0); drain; barrier ----
  {
    float4 v = *(const float4*)xrow;
    *(half4v*)adst = (half4v){(_Float16)v.x, (_Float16)v.y, (_Float16)v.z, (_Float16)v.w};
  }
#pragma unroll
  for (int it = 0; it < 4; ++it) async16(wg + it * 131072, wl0 + it * 8192);
  BARRIER_VM(0);

  for (int i = 0; i < 15; ++i) {
    // ===== h0: issue Wh1(i); load A(i+1); MFMA half0 from wTh0 = W_h0(i) ====
#pragma unroll
    for (int it = 0; it < 4; ++it)
      async16(wg + 524288 + it * 131072 + i * 64, wl1 + it * 8192);
    const float* sp = (i + 1 < 8) ? (xrow + (i + 1) * 32) : (hrow + (i - 7) * 32);
    float4 av = *(const float4*)sp;  // in flight across barrier1 (younger than Wh1? no: issued after -> survives vmcnt(1))
    half8 af[4];
#pragma unroll
    for (int s = 0; s < 4; ++s)
      af[s] = *(const half8*)(abuf + (s * 16 + l15) * 32 + aslot * 8);
    {
      half8 bf[4];
#pragma unroll
      for (int cc = 0; cc < 4; ++cc)
        bf[cc] = *(const half8*)(wTh0 + (wave * 64 + cc * 16 + l15) * 32 + aslot * 8);
      __builtin_amdgcn_s_setprio(1);
#pragma unroll
      for (int s = 0; s < 4; ++s)
#pragma unroll
        for (int cc = 0; cc < 4; ++cc)
          acc[s][cc] = __builtin_amdgcn_mfma_f32_16x16x32_f16(af[s], bf[cc], acc[s][cc], 0, 0, 0);
      __builtin_amdgcn_s_setprio(0);
    }
    BARRIER_VM(1);  // Wh1(i) in LDS for all waves; av still in flight

    // ===== h1: issue Wh0(i+1); MFMA half1 from wTh1 = W_h1(i); write A =====
#pragma unroll
    for (int it = 0; it < 4; ++it)
      async16(wg + it * 131072 + (i + 1) * 64, wl0 + it * 8192);
    {
      half8 bf[4];
#pragma unroll
      for (int cc = 0; cc < 4; ++cc)
        bf[cc] = *(const half8*)(wTh1 + (wave * 64 + cc * 16 + l15) * 32 + aslot * 8);
      __builtin_amdgcn_s_setprio(1);
#pragma unroll
      for (int s = 0; s < 4; ++s)
#pragma unroll
        for (int cc = 0; cc < 4; ++cc)
          acc[s][4 + cc] =
              __builtin_amdgcn_mfma_f32_16x16x32_f16(af[s], bf[cc], acc[s][4 + cc], 0, 0, 0);
      __builtin_amdgcn_s_setprio(0);
    }
    // A(i+1) -> abuf (readers of A(i) finished before barrier1 this iter;
    // compiler inserts the counted vmcnt wait for av here, ~400cy after issue)
    *(half4v*)adst = (half4v){(_Float16)av.x, (_Float16)av.y, (_Float16)av.z, (_Float16)av.w};
    BARRIER_VM(0);  // Wh0(i+1) in LDS + A write visible
  }
  {  // ---- peeled iter 15 ----
#pragma unroll
    for (int it = 0; it < 4; ++it)
      async16(wg + 524288 + it * 131072 + 15 * 64, wl1 + it * 8192);
    half8 af[4];
#pragma unroll
    for (int s = 0; s < 4; ++s)
      af[s] = *(const half8*)(abuf + (s * 16 + l15) * 32 + aslot * 8);
    {
      half8 bf[4];
#pragma unroll
      for (int cc = 0; cc < 4; ++cc)
        bf[cc] = *(const half8*)(wTh0 + (wave * 64 + cc * 16 + l15) * 32 + aslot * 8);
      __builtin_amdgcn_s_setprio(1);
#pragma unroll
      for (int s = 0; s < 4; ++s)
#pragma unroll
        for (int cc = 0; cc < 4; ++cc)
          acc[s][cc] = __builtin_amdgcn_mfma_f32_16x16x32_f16(af[s], bf[cc], acc[s][cc], 0, 0, 0);
      __builtin_amdgcn_s_setprio(0);
    }
    BARRIER_VM(0);  // Wh1(15) landed
    {
      half8 bf[4];
#pragma unroll
      for (int cc = 0; cc < 4; ++cc)
        bf[cc] = *(const half8*)(wTh1 + (wave * 64 + cc * 16 + l15) * 32 + aslot * 8);
      __builtin_amdgcn_s_setprio(1);
#pragma unroll
      for (int s = 0; s < 4; ++s)
#pragma unroll
        for (int cc = 0; cc < 4; ++cc)
          acc[s][4 + cc] =
              __builtin_amdgcn_mfma_f32_16x16x32_f16(af[s], bf[cc], acc[s][4 + cc], 0, 0, 0);
      __builtin_amdgcn_s_setprio(0);
    }
  }

  // ---- Epilogue: 4 passes of 16 rows (pass p == row-stripe p) ----
  // preT store: bias folded; row-slot flip (slot = row ^ 2*bit4(n)) via
  // pair-swapped vector (R3-proven). LN params staged to LDS in pass 0.
  float* out_h = out;
  float* out_c = out + (size_t)65536 * 256;
  const int er = tid >> 5;  // row in pass 0..15
  const int et = tid & 31;  // col phase: cols {et, et+32, ..., et+224}
  const int ro = er ^ (((et >> 4) & 1) << 1);  // read slot (bit4(n) == bit4(et))

#pragma unroll
  for (int p = 0; p < 4; ++p) {
    bar_lgkm();  // all waves done reading K-loop LDS (p=0) / prev pass (p>0)
    if (p == 0) {  // stage LN params (region overlays wTh1: safe after bar)
      g1l[tid] = g1[tid];
      g1l[tid + 512] = g1[tid + 512];
      b1l[tid] = b1[tid];
      b1l[tid + 512] = b1[tid + 512];
      if (tid < 256) {
        g2l[tid] = g2[tid];
        b2l[tid] = b2[tid];
      }
    }
    // write acc stripe p -> preT (col-major [n][slot]), b64 per 4 rows
#pragma unroll
    for (int c = 0; c < 8; ++c) {
      int n = ((c >> 2) << 9) + wave * 64 + ((c & 3) << 4) + l15;  // D col = lane&15
      float bn = bias[n];
      float4v a = acc[p][c];
      _Float16 e0 = (_Float16)(a.x + bn), e1 = (_Float16)(a.y + bn);
      _Float16 e2 = (_Float16)(a.z + bn), e3 = (_Float16)(a.w + bn);
      // bit4(n) == c&1: flip swaps row pairs {0,1}<->{2,3} within the quad
      half4v hv = (c & 1) ? (half4v){e2, e3, e0, e1} : (half4v){e0, e1, e2, e3};
      *(half4v*)(preT + n * PRE_STRIDE + (quad << 2)) = hv;  // rows quad*4+reg
    }
    bar_lgkm();

    const int rg = blockRow + (p << 4) + er;
    // LN1 stats per 256-chunk (bias already folded into preT)
    float mean1[4], rstd1[4];
#pragma unroll
    for (int ch = 0; ch < 4; ++ch) {
      float s = 0.f, q = 0.f;
#pragma unroll
      for (int ss = 0; ss < 8; ++ss) {
        int n = (ch << 8) + (ss << 5) + et;
        float v = (float)preT[n * PRE_STRIDE + ro];
        s += v;
        q += v * v;
      }
#pragma unroll
      for (int m = 1; m < 32; m <<= 1) {
        s += __shfl_xor(s, m, 32);
        q += __shfl_xor(q, m, 32);
      }
      float mu = s * (1.0f / 256.0f);
      mean1[ch] = mu;
      rstd1[ch] = __frsqrt_rn(q * (1.0f / 256.0f) - mu * mu + 1e-5f);
    }

    float ncp[8], so[8], cv[8];
    float s2 = 0.f, q2 = 0.f;
#pragma unroll
    for (int ss = 0; ss < 8; ++ss) {
      int hc = (ss << 5) + et;
      float iv = ((float)preT[(hc)*PRE_STRIDE + ro] - mean1[0]) * rstd1[0] * g1l[hc] + b1l[hc];
      float jv = ((float)preT[(256 + hc) * PRE_STRIDE + ro] - mean1[1]) * rstd1[1] * g1l[256 + hc] + b1l[256 + hc];
      float fv = ((float)preT[(512 + hc) * PRE_STRIDE + ro] - mean1[2]) * rstd1[2] * g1l[512 + hc] + b1l[512 + hc];
      float ov = ((float)preT[(768 + hc) * PRE_STRIDE + ro] - mean1[3]) * rstd1[3] * g1l[768 + hc] + b1l[768 + hc];
      float cval = cin[(size_t)rg * 256 + hc];
      float nc = cval * sigm(fv + 1.0f) + sigm(iv) * tanh_fast(jv);
      ncp[ss] = nc;
      so[ss] = sigm(ov);
      cv[ss] = cval;
      s2 += nc;
      q2 += nc * nc;
    }
#pragma unroll
    for (int m = 1; m < 32; m <<= 1) {
      s2 += __shfl_xor(s2, m, 32);
      q2 += __shfl_xor(q2, m, 32);
    }
    float mu2 = s2 * (1.0f / 256.0f);
    float rstd2 = __frsqrt_rn(q2 * (1.0f / 256.0f) - mu2 * mu2 + 1e-5f);
#pragma unroll
    for (int ss = 0; ss < 8; ++ss) {
      int hc = (ss << 5) + et;
      size_t gi = (size_t)rg * 256 + hc;
      float ncn = (ncp[ss] - mu2) * rstd2 * g2l[hc] + b2l[hc];
      float nh = tanh_fast(ncn) * so[ss];
      float hval = hin[gi];
      out_h[gi] = (mhp[gi] < 0.7f) ? nh : hval;  // zoneout: mask<keep -> new
      out_c[gi] = (mcp[gi] < 0.7f) ? ncn : cv[ss];
    }
  }
}

extern "C" void kernel_launch(void* const* d_in, const int* in_sizes, int n_in,
                              void* d_out, int out_size, void* d_ws, size_t ws_size,
                              hipStream_t stream) {
  (void)in_sizes; (void)n_in; (void)out_size; (void)ws_size;
  const float* x = (const float*)d_in[0];
  const float* h = (const float*)d_in[1];
  const float* c = (const float*)d_in[2];
  const float* W = (const float*)d_in[3];
  const float* bias = (const float*)d_in[4];
  const float* g1 = (const float*)d_in[5];
  const float* b1 = (const float*)d_in[6];
  const float* g2 = (const float*)d_in[7];
  const float* b2 = (const float*)d_in[8];
  const float* mh = (const float*)d_in[9];
  const float* mc = (const float*)d_in[10];
  _Float16* Wt = (_Float16*)d_ws;  // 1 MB

  wt_kernel<<<dim3(16, 8), dim3(256), 0, stream>>>(W, Wt);
  lstm_fused<<<dim3(1024), dim3(NTHREADS), 69632, stream>>>(
      x, h, c, Wt, bias, g1, b1, g2, b2, mh, mc, (float*)d_out);
}